// Round 2
// baseline (4904.354 us; speedup 1.0000x reference)
//
#include <hip/hip_runtime.h>

typedef _Float16 v8h __attribute__((ext_vector_type(8)));
typedef _Float16 v4h __attribute__((ext_vector_type(4)));
typedef float    v4f __attribute__((ext_vector_type(4)));

#define BATCH   128
#define TSTEPS  256
#define DFEAT   256
#define UDIM    1024
#define KTOT    1280        // DFEAT + UDIM
#define NCOL    2048
#define ASTRIDE 1288        // LDS A stride in halfs (pad 8 -> 2-way bank alias, free)

// Grid: 256 blocks x 1024 threads. g = blockIdx%8 (row group, 16 rows, ~1 XCD),
// cb = blockIdx/8 (col block, 32 u-cols + 32 partner a-cols).
// Wave w (0..15): cg = w&3 (16-col tile: 8 f-cols, 8 a-cols), ks = w>>2 (K-slice of 320).
// Weights: fp16, wave-stationary in VGPRs (10 chunks x v8h = 40 VGPRs).

__global__ __launch_bounds__(1024)
void ltc_rnn_kernel(const float* __restrict__ features,  // [128,256,256]
                    const float* __restrict__ tsteps,    // [128,256]
                    const float* __restrict__ Wx,        // [256,2048]
                    const float* __restrict__ Wh,        // [1024,2048]
                    const float* __restrict__ bias,      // [2048]
                    const float* __restrict__ wtau,      // [1024]
                    const float* __restrict__ h0,        // [128,1024]
                    float* __restrict__ out,             // [128,256,1024]
                    unsigned* __restrict__ counters,     // 8 groups, stride 16 u32
                    float* __restrict__ hbufs)           // 2 x [128,1024] fp32
{
  __shared__ _Float16 Alds[16 * ASTRIDE];       // [row 0..15][k 0..1279] fp16
  __shared__ float    Plds[16 * 64 * 4];        // [wave][lane][4] fp32 partials
  __shared__ float    dtlds[16];

  const int tid  = threadIdx.x;
  const int w    = tid >> 6;
  const int lane = tid & 63;
  const int n    = lane & 15;
  const int q    = lane >> 4;
  const int cg   = w & 3;
  const int ks   = w >> 2;
  const int g    = blockIdx.x & 7;       // row group
  const int cb   = blockIdx.x >> 3;      // col block
  const int u0   = cb * 32;

  // ---- load wave-stationary weights (fp32 -> fp16, once) ----
  const int gcol = (n < 8) ? (u0 + cg * 8 + n) : (UDIM + u0 + cg * 8 + (n - 8));
  v8h bfr[10];
  #pragma unroll
  for (int c = 0; c < 10; ++c) {
    #pragma unroll
    for (int j = 0; j < 8; ++j) {
      const int k = ks * 320 + c * 32 + q * 8 + j;
      const float wv = (k < DFEAT) ? Wx[(size_t)k * NCOL + gcol]
                                   : Wh[(size_t)(k - DFEAT) * NCOL + gcol];
      bfr[c][j] = (_Float16)wv;
    }
  }

  const float bias_own = bias[gcol];
  const int   u_lane   = u0 + cg * 8 + (n & 7);          // this lane's u column
  const float tau      = logf(1.0f + __expf(wtau[u_lane]));  // softplus

  // fp32 h state in registers (only meaningful on n<8 lanes of ks==0 waves)
  float h_reg[4];
  #pragma unroll
  for (int i = 0; i < 4; ++i) {
    const int row = g * 16 + q * 4 + i;
    h_reg[i] = h0[(size_t)row * UDIM + u_lane];
  }

  float* hb0 = hbufs;
  float* hb1 = hbufs + BATCH * UDIM;

  for (int t = 0; t < TSTEPS; ++t) {
    const float* hsrc = (t == 0) ? h0 : ((t & 1) ? hb1 : hb0);
    float*       hdst = ((t + 1) & 1) ? hb1 : hb0;

    // ---- stage A = [x_t ; h_t] fp32 -> fp16 into LDS ----
    if (tid < 16) dtlds[tid] = tsteps[(size_t)(g * 16 + tid) * TSTEPS + t];
    {
      // x part: 16 rows x 256 = 1024 float4, one per thread
      const int r  = tid >> 6;
      const int k4 = tid & 63;
      v4f x4 = *(const v4f*)(features + (size_t)(g * 16 + r) * (TSTEPS * DFEAT)
                             + (size_t)t * DFEAT + k4 * 4);
      v4h xh = {(_Float16)x4.x, (_Float16)x4.y, (_Float16)x4.z, (_Float16)x4.w};
      *(v4h*)&Alds[r * ASTRIDE + k4 * 4] = xh;
      // h part: 16 rows x 1024 = 4096 float4, four per thread
      #pragma unroll
      for (int jj = 0; jj < 4; ++jj) {
        const int idx4 = tid + jj * 1024;
        const int hr   = idx4 >> 8;
        const int hk4  = idx4 & 255;
        v4f h4 = *(const v4f*)(hsrc + (size_t)(g * 16 + hr) * UDIM + hk4 * 4);
        v4h hh = {(_Float16)h4.x, (_Float16)h4.y, (_Float16)h4.z, (_Float16)h4.w};
        *(v4h*)&Alds[hr * ASTRIDE + DFEAT + hk4 * 4] = hh;
      }
    }
    __syncthreads();

    // ---- MFMA: 16 rows x 16 cols x K-slice 320 ----
    {
      v4f acc = {0.f, 0.f, 0.f, 0.f};
      const _Float16* abase = &Alds[n * ASTRIDE + ks * 320 + q * 8];
      #pragma unroll
      for (int c = 0; c < 10; ++c) {
        v8h a = *(const v8h*)(abase + c * 32);
        acc = __builtin_amdgcn_mfma_f32_16x16x32_f16(a, bfr[c], acc, 0, 0, 0);
      }
      *(v4f*)&Plds[(w * 64 + lane) * 4] = acc;
    }
    __syncthreads();

    // ---- reduce K-slices + elementwise (ks==0 waves only) ----
    if (w < 4) {
      v4f p = *(v4f*)&Plds[((0 * 4 + w) * 64 + lane) * 4];
      #pragma unroll
      for (int s = 1; s < 4; ++s) {
        v4f ps = *(v4f*)&Plds[((s * 4 + w) * 64 + lane) * 4];
        p.x += ps.x; p.y += ps.y; p.z += ps.z; p.w += ps.w;
      }
      float pf[4], pa[4];
      #pragma unroll
      for (int i = 0; i < 4; ++i) {
        const float v = p[i] + bias_own;
        const float o = __shfl_xor(v, 8);
        pf[i] = v;   // n<8: own col = f
        pa[i] = o;   //       partner = a
      }
      if (n < 8) {
        #pragma unroll
        for (int i = 0; i < 4; ++i) {
          const int   row_l = q * 4 + i;
          const int   row   = g * 16 + row_l;
          const float dt    = dtlds[row_l];
          const float f     = 1.0f / (1.0f + __expf(-pf[i]));
          const float av    = 2.0f / (1.0f + __expf(-2.0f * pa[i])) - 1.0f;  // tanh
          const float decay = __expf(-dt * (tau + f));
          const float hn    = (h_reg[i] - av) * decay + av;
          h_reg[i] = hn;
          hdst[(size_t)row * UDIM + u_lane] = hn;
          out[(size_t)row * (TSTEPS * UDIM) + (size_t)t * UDIM + u_lane] = hn;
        }
      }
    }
    __syncthreads();   // all h-writes drained (vmcnt(0) before barrier)

    // ---- group barrier: 32 col-blocks of this row group ----
    if (t != TSTEPS - 1) {
      if (tid == 0) {
        __threadfence();                       // release
        atomicAdd(&counters[g * 16], 1u);
        const unsigned tgt = 32u * (unsigned)(t + 1);
        while (__hip_atomic_load(&counters[g * 16], __ATOMIC_ACQUIRE,
                                 __HIP_MEMORY_SCOPE_AGENT) < tgt)
          __builtin_amdgcn_s_sleep(2);
        __threadfence();                       // acquire
      }
      __syncthreads();
    }
  }
}

extern "C" void kernel_launch(void* const* d_in, const int* in_sizes, int n_in,
                              void* d_out, int out_size, void* d_ws, size_t ws_size,
                              hipStream_t stream) {
  const float* features = (const float*)d_in[0];
  const float* tsamp    = (const float*)d_in[1];
  const float* Wx       = (const float*)d_in[2];
  const float* Wh       = (const float*)d_in[3];
  const float* bias     = (const float*)d_in[4];
  const float* wtau     = (const float*)d_in[5];
  const float* h0       = (const float*)d_in[6];
  float*    out      = (float*)d_out;
  unsigned* counters = (unsigned*)d_ws;
  float*    hbufs    = (float*)((char*)d_ws + 4096);

  hipMemsetAsync(d_ws, 0, 1024, stream);   // zero barrier counters (ws is poisoned)
  hipLaunchKernelGGL(ltc_rnn_kernel, dim3(256), dim3(1024), 0, stream,
                     features, tsamp, Wx, Wh, bias, wtau, h0, out, counters, hbufs);
}

// Round 3
// 1122.302 us; speedup vs baseline: 4.3699x; 4.3699x over previous
//
#include <hip/hip_runtime.h>

typedef _Float16 v8h  __attribute__((ext_vector_type(8)));
typedef _Float16 v4h  __attribute__((ext_vector_type(4)));
typedef float    v4f  __attribute__((ext_vector_type(4)));
typedef unsigned int u32x4 __attribute__((ext_vector_type(4)));

#define BATCH   128
#define TSTEPS  256
#define DFEAT   256
#define UDIM    1024
#define KTOT    1280
#define NCOL    2048
#define ASTRIDE 1288   // LDS A stride (halfs); 2576B row stride, 16B-aligned

// 256 blocks x 1024 threads. g = blockIdx%8 (row group of 16 batch rows),
// cb = blockIdx/8 (32 col-blocks: 32 u-cols + 32 partner a-cols each).
// Wave w: cg = w&3 (16-col MFMA tile), ks = w>>2 (K-slice of 320).
// h exchanged in fp16 via sc0/sc1 (IC-coherent) loads/stores: NO cache-flush fences.

__global__ __launch_bounds__(1024)
void ltc_rnn_kernel(const float* __restrict__ features,  // [128,256,256]
                    const float* __restrict__ tsteps,    // [128,256]
                    const float* __restrict__ Wx,        // [256,2048]
                    const float* __restrict__ Wh,        // [1024,2048]
                    const float* __restrict__ bias,      // [2048]
                    const float* __restrict__ wtau,      // [1024]
                    const float* __restrict__ h0,        // [128,1024]
                    float* __restrict__ out,             // [128,256,1024]
                    unsigned* __restrict__ counters,     // 8 groups, stride 64 u32
                    _Float16* __restrict__ hbufs)        // 2 x [128,1024] fp16
{
  __shared__ _Float16 Alds[16 * ASTRIDE];   // [row][k] fp16, x part k<256, h part k>=256
  __shared__ float    Plds[16 * 64 * 4];    // per-wave MFMA partials
  __shared__ _Float16 Hout[16][32];         // packed h tile (u cols only)
  __shared__ float    OutT[16][32];         // packed out tile
  __shared__ float    dtlds[2][16];

  const int tid  = threadIdx.x;
  const int w    = tid >> 6;
  const int lane = tid & 63;
  const int n    = lane & 15;
  const int q    = lane >> 4;
  const int cg   = w & 3;
  const int ks   = w >> 2;
  const int g    = blockIdx.x & 7;
  const int cb   = blockIdx.x >> 3;
  const int u0   = cb * 32;

  // ---- wave-stationary weights: fp32 -> fp16 VGPRs, once ----
  const int gcol = (n < 8) ? (u0 + cg * 8 + n) : (UDIM + u0 + cg * 8 + (n - 8));
  v8h bfr[10];
  #pragma unroll
  for (int c = 0; c < 10; ++c) {
    #pragma unroll
    for (int j = 0; j < 8; ++j) {
      const int k = ks * 320 + c * 32 + q * 8 + j;
      const float wv = (k < DFEAT) ? Wx[(size_t)k * NCOL + gcol]
                                   : Wh[(size_t)(k - DFEAT) * NCOL + gcol];
      bfr[c][j] = (_Float16)wv;
    }
  }

  const float bias_own = bias[gcol];
  const int   u_lane   = u0 + cg * 8 + (n & 7);
  const float tau      = logf(1.0f + __expf(wtau[u_lane]));

  float h_reg[4];
  #pragma unroll
  for (int i = 0; i < 4; ++i)
    h_reg[i] = h0[(size_t)(g * 16 + q * 4 + i) * UDIM + u_lane];

  // ---- pre-loop staging: x(0), dt(0), h0 ----
  if (tid < 16) dtlds[0][tid] = tsteps[(size_t)(g * 16 + tid) * TSTEPS + 0];
  {
    const int r = tid >> 6, k4 = tid & 63;
    v4f x4 = *(const v4f*)(features + (size_t)(g * 16 + r) * (TSTEPS * DFEAT) + k4 * 4);
    v4h xh = {(_Float16)x4.x, (_Float16)x4.y, (_Float16)x4.z, (_Float16)x4.w};
    *(v4h*)&Alds[r * ASTRIDE + k4 * 4] = xh;
    #pragma unroll
    for (int jj = 0; jj < 4; ++jj) {
      const int c = tid + jj * 1024, hr = c >> 8, hk4 = c & 255;
      v4f h4 = *(const v4f*)(h0 + (size_t)(g * 16 + hr) * UDIM + hk4 * 4);
      v4h hh = {(_Float16)h4.x, (_Float16)h4.y, (_Float16)h4.z, (_Float16)h4.w};
      *(v4h*)&Alds[hr * ASTRIDE + DFEAT + hk4 * 4] = hh;
    }
  }
  __syncthreads();

  for (int t = 0; t < TSTEPS; ++t) {
    _Float16* hdst = hbufs + ((t + 1) & 1) * (BATCH * UDIM);

    // ---- MFMA: 16 rows x 16 cols x K-slice 320 ----
    {
      v4f acc = {0.f, 0.f, 0.f, 0.f};
      const _Float16* abase = &Alds[n * ASTRIDE + ks * 320 + q * 8];
      #pragma unroll
      for (int c = 0; c < 10; ++c) {
        v8h a = *(const v8h*)(abase + c * 32);
        acc = __builtin_amdgcn_mfma_f32_16x16x32_f16(a, bfr[c], acc, 0, 0, 0);
      }
      *(v4f*)&Plds[(w * 64 + lane) * 4] = acc;
    }
    __syncthreads();

    // ---- reduce K-slices + elementwise (waves 0..3) ----
    if (w < 4) {
      v4f p = *(v4f*)&Plds[((0 * 4 + w) * 64 + lane) * 4];
      #pragma unroll
      for (int s = 1; s < 4; ++s) {
        v4f ps = *(v4f*)&Plds[((s * 4 + w) * 64 + lane) * 4];
        p.x += ps.x; p.y += ps.y; p.z += ps.z; p.w += ps.w;
      }
      float pf[4], pa[4];
      #pragma unroll
      for (int i = 0; i < 4; ++i) {
        const float v = p[i] + bias_own;
        const float o = __shfl_xor(v, 8);
        pf[i] = v; pa[i] = o;
      }
      if (n < 8) {
        #pragma unroll
        for (int i = 0; i < 4; ++i) {
          const int   row_l = q * 4 + i;
          const float dt    = dtlds[t & 1][row_l];
          const float f     = 1.0f / (1.0f + __expf(-pf[i]));
          const float av    = 2.0f / (1.0f + __expf(-2.0f * pa[i])) - 1.0f;
          const float decay = __expf(-dt * (tau + f));
          const float hn    = (h_reg[i] - av) * decay + av;
          h_reg[i] = hn;
          Hout[row_l][cg * 8 + n] = (_Float16)hn;
          OutT[row_l][cg * 8 + n] = hn;
        }
      }
    }
    __syncthreads();

    // ---- prefetch x(t+1), dt(t+1) (x LDS region is dead now) ----
    if (t + 1 < TSTEPS) {
      if (tid < 16) dtlds[(t + 1) & 1][tid] = tsteps[(size_t)(g * 16 + tid) * TSTEPS + t + 1];
      const int r = tid >> 6, k4 = tid & 63;
      v4f x4 = *(const v4f*)(features + (size_t)(g * 16 + r) * (TSTEPS * DFEAT)
                             + (size_t)(t + 1) * DFEAT + k4 * 4);
      v4h xh = {(_Float16)x4.x, (_Float16)x4.y, (_Float16)x4.z, (_Float16)x4.w};
      *(v4h*)&Alds[r * ASTRIDE + k4 * 4] = xh;
    }

    // ---- packed stores: h tile (IC-coherent) + out tile (normal) ----
    if (tid < 64) {                       // whole wave 0
      const int row = tid >> 2, c8 = tid & 3;
      v8h hv = *(v8h*)&Hout[row][c8 * 8];
      _Float16* dp = hdst + (size_t)(g * 16 + row) * UDIM + u0 + c8 * 8;
      asm volatile("global_store_dwordx4 %0, %1, off sc0 sc1\n\t"
                   "s_waitcnt vmcnt(0)"
                   :: "v"(dp), "v"(__builtin_bit_cast(u32x4, hv)) : "memory");
    } else if (tid < 192) {
      const int row = (tid - 64) >> 3, c4 = (tid - 64) & 7;
      v4f ov = *(v4f*)&OutT[row][c4 * 4];
      *(v4f*)(out + (size_t)(g * 16 + row) * (TSTEPS * UDIM)
              + (size_t)t * UDIM + u0 + c4 * 4) = ov;
    }
    __syncthreads();   // h stores drained (asm waitcnt above), tiles consumed

    if (t + 1 < TSTEPS) {
      // ---- group barrier (32 blocks), IC-resident counter, no cache flush ----
      if (tid == 0) {
        __hip_atomic_fetch_add(&counters[g * 64], 1u, __ATOMIC_RELAXED,
                               __HIP_MEMORY_SCOPE_AGENT);
        const unsigned tgt = 32u * (unsigned)(t + 1);
        while (__hip_atomic_load(&counters[g * 64], __ATOMIC_RELAXED,
                                 __HIP_MEMORY_SCOPE_AGENT) < tgt)
          __builtin_amdgcn_s_sleep(1);
      }
      __syncthreads();

      // ---- stage h(t+1) from IC (bypass L1/L2) ----
      const _Float16* hsrc = hbufs + ((t + 1) & 1) * (BATCH * UDIM);
      const int c0 = tid, c1 = tid + 1024;
      const _Float16* p0 = hsrc + (size_t)(g * 16 + (c0 >> 7)) * UDIM + (c0 & 127) * 8;
      const _Float16* p1 = hsrc + (size_t)(g * 16 + (c1 >> 7)) * UDIM + (c1 & 127) * 8;
      u32x4 r0, r1;
      asm volatile("global_load_dwordx4 %0, %2, off sc0 sc1\n\t"
                   "global_load_dwordx4 %1, %3, off sc0 sc1\n\t"
                   "s_waitcnt vmcnt(0)"
                   : "=v"(r0), "=v"(r1) : "v"(p0), "v"(p1) : "memory");
      *(v8h*)&Alds[(c0 >> 7) * ASTRIDE + DFEAT + (c0 & 127) * 8] = __builtin_bit_cast(v8h, r0);
      *(v8h*)&Alds[(c1 >> 7) * ASTRIDE + DFEAT + (c1 & 127) * 8] = __builtin_bit_cast(v8h, r1);
      __syncthreads();
    }
  }
}

extern "C" void kernel_launch(void* const* d_in, const int* in_sizes, int n_in,
                              void* d_out, int out_size, void* d_ws, size_t ws_size,
                              hipStream_t stream) {
  const float* features = (const float*)d_in[0];
  const float* tsamp    = (const float*)d_in[1];
  const float* Wx       = (const float*)d_in[2];
  const float* Wh       = (const float*)d_in[3];
  const float* bias     = (const float*)d_in[4];
  const float* wtau     = (const float*)d_in[5];
  const float* h0       = (const float*)d_in[6];
  float*     out      = (float*)d_out;
  unsigned*  counters = (unsigned*)d_ws;
  _Float16*  hbufs    = (_Float16*)((char*)d_ws + 4096);

  hipMemsetAsync(d_ws, 0, 4096, stream);   // zero barrier counters
  hipLaunchKernelGGL(ltc_rnn_kernel, dim3(256), dim3(1024), 0, stream,
                     features, tsamp, Wx, Wh, bias, wtau, h0, out, counters, hbufs);
}

// Round 4
// 1027.891 us; speedup vs baseline: 4.7713x; 1.0918x over previous
//
#include <hip/hip_runtime.h>

typedef _Float16 v8h  __attribute__((ext_vector_type(8)));
typedef _Float16 v4h  __attribute__((ext_vector_type(4)));
typedef float    v4f  __attribute__((ext_vector_type(4)));
typedef unsigned int u32x4 __attribute__((ext_vector_type(4)));

#define BATCH   128
#define TSTEPS  256
#define DFEAT   256
#define UDIM    1024
#define NCOL    2048
#define ASTRIDE 1288   // LDS A stride (halfs)

// 256 blocks x 1024 threads. g = blockIdx%8 (row group of 16 batch rows),
// cb = blockIdx/8 (32 col-blocks). Wave w: cg=w&3 (16-col tile), ks=w>>2 (K-slice 320).
// Inter-block exchange: h tile via sc0/sc1 (IC-coherent) + per-block tagged flags.
// Critical chain per step: reduce -> h pack-store (wave0) -> vmcnt -> flag -> poll -> h load.

__global__ __launch_bounds__(1024)
void ltc_rnn_kernel(const float* __restrict__ features,  // [128,256,256]
                    const float* __restrict__ tsteps,    // [128,256]
                    const float* __restrict__ Wx,        // [256,2048]
                    const float* __restrict__ Wh,        // [1024,2048]
                    const float* __restrict__ bias,      // [2048]
                    const float* __restrict__ wtau,      // [1024]
                    const float* __restrict__ h0,        // [128,1024]
                    float* __restrict__ out,             // [128,256,1024]
                    unsigned* __restrict__ flags,        // [8][64] u32 (tagged t+1)
                    _Float16* __restrict__ hbufs)        // 2 x [128,1024] fp16
{
  __shared__ _Float16 Alds[16 * ASTRIDE];
  __shared__ float    Plds[16 * 64 * 4];
  __shared__ _Float16 Hout[16][32];
  __shared__ float    dtlds[2][16];

  const int tid  = threadIdx.x;
  const int w    = tid >> 6;
  const int lane = tid & 63;
  const int n    = lane & 15;
  const int q    = lane >> 4;
  const int cg   = w & 3;
  const int ks   = w >> 2;
  const int g    = blockIdx.x & 7;
  const int cb   = blockIdx.x >> 3;
  const int u0   = cb * 32;

  // ---- wave-stationary weights: fp32 -> fp16 VGPRs, once ----
  const int gcol = (n < 8) ? (u0 + cg * 8 + n) : (UDIM + u0 + cg * 8 + (n - 8));
  v8h bfr[10];
  #pragma unroll
  for (int c = 0; c < 10; ++c) {
    #pragma unroll
    for (int j = 0; j < 8; ++j) {
      const int k = ks * 320 + c * 32 + q * 8 + j;
      const float wv = (k < DFEAT) ? Wx[(size_t)k * NCOL + gcol]
                                   : Wh[(size_t)(k - DFEAT) * NCOL + gcol];
      bfr[c][j] = (_Float16)wv;
    }
  }

  const float bias_own = bias[gcol];
  const int   u_lane   = u0 + cg * 8 + (n & 7);
  const float tau      = logf(1.0f + __expf(wtau[u_lane]));

  float h_reg[4];
  #pragma unroll
  for (int i = 0; i < 4; ++i)
    h_reg[i] = h0[(size_t)(g * 16 + q * 4 + i) * UDIM + u_lane];

  // ---- pre-loop staging: x(0), dt(0), h0 ----
  if (tid < 16) dtlds[0][tid] = tsteps[(size_t)(g * 16 + tid) * TSTEPS + 0];
  {
    const int r = tid >> 6, k4 = tid & 63;
    v4f x4 = *(const v4f*)(features + (size_t)(g * 16 + r) * (TSTEPS * DFEAT) + k4 * 4);
    v4h xh = {(_Float16)x4.x, (_Float16)x4.y, (_Float16)x4.z, (_Float16)x4.w};
    *(v4h*)&Alds[r * ASTRIDE + k4 * 4] = xh;
    #pragma unroll
    for (int jj = 0; jj < 4; ++jj) {
      const int c = tid + jj * 1024, hr = c >> 8, hk4 = c & 255;
      v4f h4 = *(const v4f*)(h0 + (size_t)(g * 16 + hr) * UDIM + hk4 * 4);
      v4h hh = {(_Float16)h4.x, (_Float16)h4.y, (_Float16)h4.z, (_Float16)h4.w};
      *(v4h*)&Alds[hr * ASTRIDE + DFEAT + hk4 * 4] = hh;
    }
  }
  __syncthreads();

  for (int t = 0; t < TSTEPS; ++t) {
    const bool more = (t + 1 < TSTEPS);
    _Float16* hdst = hbufs + ((t + 1) & 1) * (BATCH * UDIM);

    // ---- MFMA: 16 rows x 16 cols x K-slice 320 ----
    {
      v4f acc = {0.f, 0.f, 0.f, 0.f};
      const _Float16* abase = &Alds[n * ASTRIDE + ks * 320 + q * 8];
      #pragma unroll
      for (int c = 0; c < 10; ++c) {
        v8h a = *(const v8h*)(abase + c * 32);
        acc = __builtin_amdgcn_mfma_f32_16x16x32_f16(a, bfr[c], acc, 0, 0, 0);
      }
      *(v4f*)&Plds[(w * 64 + lane) * 4] = acc;
    }
    __syncthreads();                                   // S1: Plds ready

    // ---- reduce + elementwise (waves 0..3); h tile -> LDS, out vals -> regs ----
    float outv[4];
    if (w < 4) {
      v4f p = *(v4f*)&Plds[((0 * 4 + w) * 64 + lane) * 4];
      #pragma unroll
      for (int s = 1; s < 4; ++s) {
        v4f ps = *(v4f*)&Plds[((s * 4 + w) * 64 + lane) * 4];
        p.x += ps.x; p.y += ps.y; p.z += ps.z; p.w += ps.w;
      }
      float pf[4], pa[4];
      #pragma unroll
      for (int i = 0; i < 4; ++i) {
        const float v = p[i] + bias_own;
        const float o = __shfl_xor(v, 8);
        pf[i] = v; pa[i] = o;
      }
      if (n < 8) {
        #pragma unroll
        for (int i = 0; i < 4; ++i) {
          const int   row_l = q * 4 + i;
          const float dt    = dtlds[t & 1][row_l];
          const float f     = 1.0f / (1.0f + __expf(-pf[i]));
          const float av    = 2.0f / (1.0f + __expf(-2.0f * pa[i])) - 1.0f;
          const float decay = __expf(-dt * (tau + f));
          const float hn    = (h_reg[i] - av) * decay + av;
          h_reg[i] = hn;
          outv[i]  = hn;
          Hout[row_l][w * 8 + n] = (_Float16)hn;
        }
      }
    }
    __syncthreads();                                   // S2: Hout ready

    // ---- wave0: packed h-store to IC, ack, publish tagged flag ----
    if (w == 0 && more) {
      const int row = lane >> 2, c8 = lane & 3;
      v8h hv = *(v8h*)&Hout[row][c8 * 8];
      _Float16* dp = hdst + (size_t)(g * 16 + row) * UDIM + u0 + c8 * 8;
      asm volatile("global_store_dwordx4 %0, %1, off sc0 sc1\n\t"
                   "s_waitcnt vmcnt(0)"
                   :: "v"(dp), "v"(__builtin_bit_cast(u32x4, hv)) : "memory");
      if (lane == 0) {
        unsigned tg = (unsigned)(t + 1);
        asm volatile("global_store_dword %0, %1, off sc0 sc1"
                     :: "v"(&flags[g * 64 + cb]), "v"(tg) : "memory");
      }
    }

    // ---- off-critical-path: out stores + x(t+1)/dt(t+1) prefetch (drain during spin) ----
    if (w < 4 && n < 8) {
      #pragma unroll
      for (int i = 0; i < 4; ++i) {
        const int row = g * 16 + q * 4 + i;
        out[(size_t)row * (TSTEPS * UDIM) + (size_t)t * UDIM + u_lane] = outv[i];
      }
    }
    if (more) {
      if (tid < 16) dtlds[(t + 1) & 1][tid] = tsteps[(size_t)(g * 16 + tid) * TSTEPS + t + 1];
      const int r = tid >> 6, k4 = tid & 63;
      v4f x4 = *(const v4f*)(features + (size_t)(g * 16 + r) * (TSTEPS * DFEAT)
                             + (size_t)(t + 1) * DFEAT + k4 * 4);
      v4h xh = {(_Float16)x4.x, (_Float16)x4.y, (_Float16)x4.z, (_Float16)x4.w};
      *(v4h*)&Alds[r * ASTRIDE + k4 * 4] = xh;
    }

    // ---- wave0: spin on the 32-flag line (one coalesced load per poll) ----
    if (w == 0 && more) {
      const unsigned* fp = &flags[g * 64 + (lane & 31)];
      const unsigned  tg = (unsigned)t;      // stale if flag <= t
      for (;;) {
        unsigned v;
        asm volatile("global_load_dword %0, %1, off sc0 sc1\n\t"
                     "s_waitcnt vmcnt(0)"
                     : "=v"(v) : "v"(fp) : "memory");
        if (__ballot(v <= tg) == 0ull) break;
      }
    }
    __syncthreads();                                   // S3: all flags seen; prefetches drained

    // ---- stage h(t+1) from IC into LDS ----
    if (more) {
      const _Float16* hsrc = hbufs + ((t + 1) & 1) * (BATCH * UDIM);
      const int c0 = tid, c1 = tid + 1024;
      const _Float16* p0 = hsrc + (size_t)(g * 16 + (c0 >> 7)) * UDIM + (c0 & 127) * 8;
      const _Float16* p1 = hsrc + (size_t)(g * 16 + (c1 >> 7)) * UDIM + (c1 & 127) * 8;
      u32x4 r0, r1;
      asm volatile("global_load_dwordx4 %0, %2, off sc0 sc1\n\t"
                   "global_load_dwordx4 %1, %3, off sc0 sc1\n\t"
                   "s_waitcnt vmcnt(0)"
                   : "=v"(r0), "=v"(r1) : "v"(p0), "v"(p1) : "memory");
      *(v8h*)&Alds[(c0 >> 7) * ASTRIDE + DFEAT + (c0 & 127) * 8] = __builtin_bit_cast(v8h, r0);
      *(v8h*)&Alds[(c1 >> 7) * ASTRIDE + DFEAT + (c1 & 127) * 8] = __builtin_bit_cast(v8h, r1);
      __syncthreads();                                 // S4: A(t+1) ready
    }
  }
}

extern "C" void kernel_launch(void* const* d_in, const int* in_sizes, int n_in,
                              void* d_out, int out_size, void* d_ws, size_t ws_size,
                              hipStream_t stream) {
  const float* features = (const float*)d_in[0];
  const float* tsamp    = (const float*)d_in[1];
  const float* Wx       = (const float*)d_in[2];
  const float* Wh       = (const float*)d_in[3];
  const float* bias     = (const float*)d_in[4];
  const float* wtau     = (const float*)d_in[5];
  const float* h0       = (const float*)d_in[6];
  float*     out    = (float*)d_out;
  unsigned*  flags  = (unsigned*)d_ws;
  _Float16*  hbufs  = (_Float16*)((char*)d_ws + 4096);

  hipMemsetAsync(d_ws, 0, 4096, stream);   // zero flags (ws is poisoned)
  hipLaunchKernelGGL(ltc_rnn_kernel, dim3(256), dim3(1024), 0, stream,
                     features, tsamp, Wx, Wh, bias, wtau, h0, out, flags, hbufs);
}